// Round 5
// baseline (642.794 us; speedup 1.0000x reference)
//
#include <hip/hip_runtime.h>
#include <math.h>

typedef _Float16 f16;
using f16x8 = __attribute__((ext_vector_type(8))) _Float16;
using f32x4 = __attribute__((ext_vector_type(4))) float;

#define BATCH 2
#define SEQ   2048
#define DMODEL 4096
#define NH    32
#define NKV   8
#define HD    128
#define MTOK  (BATCH*SEQ)

// ---------------- f32 -> f16 convert ----------------
__global__ __launch_bounds__(256) void cvt_f32_f16_k(const float* __restrict__ in,
                                                     f16* __restrict__ out, int n8) {
  int i = blockIdx.x * 256 + threadIdx.x;
  if (i >= n8) return;
  const float4* p = reinterpret_cast<const float4*>(in) + (size_t)i * 2;
  float4 a = p[0], b = p[1];
  f16x8 o = { (f16)a.x, (f16)a.y, (f16)a.z, (f16)a.w,
              (f16)b.x, (f16)b.y, (f16)b.z, (f16)b.w };
  reinterpret_cast<f16x8*>(out)[i] = o;
}

// ------------- w[K][N] f32 -> wT[N][K] f16 -------------
__global__ __launch_bounds__(256) void transpose_cvt_k(const float* __restrict__ w,
                                                       f16* __restrict__ wt, int Kd, int Nd) {
  __shared__ float tile[32][33];
  const int t = threadIdx.x;
  const int n0 = blockIdx.x * 32, k0 = blockIdx.y * 32;
  const int r = t >> 3, c4 = (t & 7) << 2;
  const float4 v = *reinterpret_cast<const float4*>(w + (size_t)(k0 + r) * Nd + n0 + c4);
  tile[r][c4 + 0] = v.x; tile[r][c4 + 1] = v.y; tile[r][c4 + 2] = v.z; tile[r][c4 + 3] = v.w;
  __syncthreads();
  union { f16 h[4]; ushort4 u4; } pk;
  pk.h[0] = (f16)tile[c4 + 0][r];
  pk.h[1] = (f16)tile[c4 + 1][r];
  pk.h[2] = (f16)tile[c4 + 2][r];
  pk.h[3] = (f16)tile[c4 + 3][r];
  *reinterpret_cast<ushort4*>(wt + (size_t)(n0 + r) * Kd + k0 + c4) = pk.u4;
}

// ------------- 128^2 GEMM. MODE 3: merged K|V projection (N=2048):
//   ncol<1024 -> K[B,S,NKV,HD] (row stride 1024); ncol>=1024 -> VT[B,NKV,HD,SEQ]
template<int MODE>
__global__ __launch_bounds__(256) void gemm_bt_k(const f16* __restrict__ A,
                                                 const f16* __restrict__ BT,
                                                 void* __restrict__ Cv,
                                                 int M, int N, int K) {
  __shared__ f16 Alds[128 * 64];
  __shared__ f16 Blds[128 * 64];
  const int t = threadIdx.x, lane = t & 63, w = t >> 6;
  const int nbn = N >> 7;
  const int nwg = gridDim.x;
  const int cpx = nwg >> 3;
  const int bid = blockIdx.x;
  const int swz = (bid & 7) * cpx + (bid >> 3);
  const int bm = swz / nbn, bn = swz % nbn;
  const size_t m0 = (size_t)bm << 7, n0 = (size_t)bn << 7;

  const int srow = t >> 3;
  const int sslot = t & 7;
  char* ldsAw = (char*)Alds + w * 1024;
  char* ldsBw = (char*)Blds + w * 1024;

  f32x4 acc[4][4];
#pragma unroll
  for (int i = 0; i < 4; i++)
#pragma unroll
    for (int j = 0; j < 4; j++) acc[i][j] = f32x4{0.f, 0.f, 0.f, 0.f};

  const int wr = (w >> 1) << 6, wc = (w & 1) << 6;
  const int ll = lane & 15, lg = lane >> 4;

  for (int kt = 0; kt < K; kt += 64) {
    __syncthreads();
#pragma unroll
    for (int p = 0; p < 4; p++) {
      const int row = srow + (p << 5);
      const int ssrc = (sslot ^ (row & 7)) << 3;
      const f16* gA = A + (m0 + row) * (size_t)K + kt + ssrc;
      __builtin_amdgcn_global_load_lds((const __attribute__((address_space(1))) void*)gA,
          (__attribute__((address_space(3))) void*)(ldsAw + p * 4096), 16, 0, 0);
      const f16* gB = BT + (n0 + row) * (size_t)K + kt + ssrc;
      __builtin_amdgcn_global_load_lds((const __attribute__((address_space(1))) void*)gB,
          (__attribute__((address_space(3))) void*)(ldsBw + p * 4096), 16, 0, 0);
    }
    __syncthreads();
#pragma unroll
    for (int kk = 0; kk < 2; kk++) {
      f16x8 af[4], bfr[4];
      const int slot = (kk << 2) + lg;
#pragma unroll
      for (int i = 0; i < 4; i++) {
        const int r = wr + (i << 4) + ll;
        af[i] = *reinterpret_cast<const f16x8*>((const char*)Alds + r * 128 + ((slot ^ (r & 7)) << 4));
      }
#pragma unroll
      for (int j = 0; j < 4; j++) {
        const int r = wc + (j << 4) + ll;
        bfr[j] = *reinterpret_cast<const f16x8*>((const char*)Blds + r * 128 + ((slot ^ (r & 7)) << 4));
      }
#pragma unroll
      for (int i = 0; i < 4; i++)
#pragma unroll
        for (int j = 0; j < 4; j++)
          acc[i][j] = __builtin_amdgcn_mfma_f32_16x16x32_f16(af[i], bfr[j], acc[i][j], 0, 0, 0);
    }
  }

#pragma unroll
  for (int i = 0; i < 4; i++) {
    const size_t mrow = m0 + wr + (i << 4) + (lg << 2);
#pragma unroll
    for (int j = 0; j < 4; j++) {
      const size_t ncol = n0 + wc + (j << 4) + ll;
      if (MODE == 0) {
        f16* C = (f16*)Cv;
#pragma unroll
        for (int r = 0; r < 4; r++) C[(mrow + r) * N + ncol] = (f16)acc[i][j][r];
      } else if (MODE == 2) {
        float* C = (float*)Cv;
#pragma unroll
        for (int r = 0; r < 4; r++) C[(mrow + r) * N + ncol] = acc[i][j][r];
      } else if (MODE == 3) {
        f16* Kc = (f16*)Cv;
        f16* Vt = (f16*)Cv + (size_t)MTOK * NKV * HD;   // VT sits right after K in ws
        if ((int)ncol < 1024) {
#pragma unroll
          for (int r = 0; r < 4; r++) Kc[(mrow + r) * 1024 + ncol] = (f16)acc[i][j][r];
        } else {
          const int nc = (int)ncol - 1024;
          const int kvh = nc >> 7, d = nc & 127;
          const int b = (int)(mrow >> 11), sc = (int)(mrow & 2047);
          union { f16 h[4]; ushort4 u4; } pk;
#pragma unroll
          for (int r = 0; r < 4; r++) pk.h[r] = (f16)acc[i][j][r];
          *reinterpret_cast<ushort4*>(Vt + (((size_t)(b * NKV + kvh) * HD + d) * SEQ + sc)) = pk.u4;
        }
      }
    }
  }
}

// ------------- 256^2 8-phase GEMM (T2+T3+T4+T5) for the two 4096^3 GEMMs -------------
template<int MODE>
__global__ __launch_bounds__(512, 2) void gemm256_k(const f16* __restrict__ A,
                                                    const f16* __restrict__ BT,
                                                    void* __restrict__ Cv,
                                                    int M, int N, int K) {
  __shared__ f16 lds[2 * 4 * 128 * 64];   // 128 KB
  char* ldsb = (char*)lds;

  const int t = threadIdx.x, lane = t & 63, w = t >> 6;
  const int wm = w >> 2, wn = w & 3;
  const int ll = lane & 15, lg = lane >> 4;
  const int nbn = N >> 8;
  const int nwg = gridDim.x, cpx = nwg >> 3, bid = blockIdx.x;
  const int swz = (bid & 7) * cpx + (bid >> 3);
  const int bm = swz / nbn, bn = swz % nbn;
  const size_t m0 = (size_t)bm << 8, n0 = (size_t)bn << 8;
  const int NT = K >> 6;

  auto stage = [&](int bufI, int unit, int ktS) {
    const f16* base = (unit < 2) ? (A + (m0 + (size_t)(unit & 1) * 128) * (size_t)K)
                                 : (BT + (n0 + (size_t)(unit & 1) * 128) * (size_t)K);
#pragma unroll
    for (int rr = 0; rr < 2; rr++) {
      const int u = t + rr * 512;
      const int row = u >> 3, lin = u & 7;
      const int slot = lin ^ (row & 7);
      const f16* src = base + (size_t)row * K + ktS + slot * 8;
      char* dst = ldsb + (size_t)(bufI * 4 + unit) * 16384 + (size_t)(w * 64 + rr * 512) * 16;
      __builtin_amdgcn_global_load_lds((const __attribute__((address_space(1))) void*)src,
          (__attribute__((address_space(3))) void*)dst, 16, 0, 0);
    }
  };

  f32x4 acc[8][4];
#pragma unroll
  for (int i = 0; i < 8; i++)
#pragma unroll
    for (int j = 0; j < 4; j++) acc[i][j] = f32x4{0.f, 0.f, 0.f, 0.f};

  f16x8 af[4][2];
  f16x8 bfr[2][2][2];

  stage(0, 0, 0); stage(0, 2, 0); stage(0, 3, 0); stage(0, 1, 0);
  stage(1, 0, 64); stage(1, 2, 64); stage(1, 3, 64);
  asm volatile("s_waitcnt vmcnt(6)" ::: "memory");
  __builtin_amdgcn_sched_barrier(0);
  __builtin_amdgcn_s_barrier();

#define PH(RBUF, RDA, RDB, SBUF, SUNIT, STILE, VM, MH, NHQ) do {                          \
    if ((RDA) >= 0) {                                                                     \
      const char* ab = ldsb + (size_t)((RBUF) * 4 + (RDA)) * 16384;                       \
      _Pragma("unroll") for (int mi = 0; mi < 4; mi++)                                    \
        _Pragma("unroll") for (int kk = 0; kk < 2; kk++)                                  \
          af[mi][kk] = *reinterpret_cast<const f16x8*>(ab + (mi * 32 + wm * 16 + ll) * 128\
                               + ((((kk << 2) + lg) ^ (ll & 7)) << 4));                   \
    }                                                                                     \
    if ((RDB) >= 0) {                                                                     \
      const char* bb = ldsb + (size_t)((RBUF) * 4 + 2 + (RDB)) * 16384;                   \
      _Pragma("unroll") for (int ni = 0; ni < 2; ni++)                                    \
        _Pragma("unroll") for (int kk = 0; kk < 2; kk++)                                  \
          bfr[RDB][ni][kk] = *reinterpret_cast<const f16x8*>(bb +                         \
                               (wn * 32 + ni * 16 + ll) * 128                             \
                               + ((((kk << 2) + lg) ^ (ll & 7)) << 4));                   \
    }                                                                                     \
    stage((SBUF), (SUNIT), ((STILE) & (NT - 1)) << 6);                                    \
    if (VM) { asm volatile("s_waitcnt vmcnt(6)" ::: "memory");                            \
              __builtin_amdgcn_sched_barrier(0); }                                        \
    __builtin_amdgcn_s_barrier();                                                         \
    asm volatile("s_waitcnt lgkmcnt(0)" ::: "memory");                                    \
    __builtin_amdgcn_sched_barrier(0);                                                    \
    __builtin_amdgcn_s_setprio(1);                                                        \
    _Pragma("unroll") for (int kk = 0; kk < 2; kk++)                                      \
      _Pragma("unroll") for (int mi = 0; mi < 4; mi++)                                    \
        _Pragma("unroll") for (int ni = 0; ni < 2; ni++)                                  \
          acc[(MH) * 4 + mi][(NHQ) * 2 + ni] = __builtin_amdgcn_mfma_f32_16x16x32_f16(    \
              af[mi][kk], bfr[NHQ][ni][kk], acc[(MH) * 4 + mi][(NHQ) * 2 + ni], 0, 0, 0); \
    __builtin_amdgcn_s_setprio(0);                                                        \
    __builtin_amdgcn_s_barrier();                                                         \
  } while (0)

  for (int tt = 0; tt < NT; tt += 2) {
    PH(0,  0,  0, 1, 1, tt + 1, false, 0, 0);
    PH(0, -1,  1, 0, 0, tt + 2, false, 0, 1);
    PH(0,  1, -1, 0, 2, tt + 2, false, 1, 0);
    PH(0, -1, -1, 0, 3, tt + 2, true , 1, 1);
    PH(1,  0,  0, 0, 1, tt + 2, false, 0, 0);
    PH(1, -1,  1, 1, 0, tt + 3, false, 0, 1);
    PH(1,  1, -1, 1, 2, tt + 3, false, 1, 0);
    PH(1, -1, -1, 1, 3, tt + 3, true , 1, 1);
  }
#undef PH

#pragma unroll
  for (int mh = 0; mh < 2; mh++)
#pragma unroll
    for (int mi = 0; mi < 4; mi++) {
      const size_t r0 = m0 + mh * 128 + mi * 32 + wm * 16 + lg * 4;
#pragma unroll
      for (int nh = 0; nh < 2; nh++)
#pragma unroll
        for (int ni = 0; ni < 2; ni++) {
          const size_t c = n0 + nh * 128 + wn * 32 + ni * 16 + ll;
          const f32x4 v = acc[mh * 4 + mi][nh * 2 + ni];
          if (MODE == 0) {
            f16* C = (f16*)Cv;
#pragma unroll
            for (int rr = 0; rr < 4; rr++) C[(r0 + rr) * N + c] = (f16)v[rr];
          } else {
            float* C = (float*)Cv;
#pragma unroll
            for (int rr = 0; rr < 4; rr++) C[(r0 + rr) * N + c] = v[rr];
          }
        }
    }
}

// ------------- flash attention v5: T15 pipeline (QK(i) ∥ softmax/PV(i-1)) + counted vmcnt -------------
// 8 waves = 4 heads x 2 q-subtiles, 16 q/wave. Raw s_barrier; V loads stay in flight (vmcnt(2)).
__global__ __launch_bounds__(512, 4) void attn_k5(const f16* __restrict__ Q,
                                                  const f16* __restrict__ Kb,
                                                  const f16* __restrict__ VT,
                                                  f16* __restrict__ ctx) {
  __shared__ f16 Klds[2][64 * 128];   // 16 KB x2
  __shared__ f16 Vlds[2][128 * 64];   // 16 KB x2
  __shared__ f16 Plds[8][16 * 64];    // 2 KB/wave (total 80 KB)

  const int t = threadIdx.x, lane = t & 63, w = t >> 6;
  const int bid = blockIdx.x;
  const int swz = (bid & 7) * 128 + (bid >> 3);
  const int qt = swz & 63, kvh = (swz >> 6) & 7, b = swz >> 9;
  const int h = kvh * 4 + (w & 3);
  const int q0 = qt * 32 + (w >> 2) * 16;
  const int ll = lane & 15, lg = lane >> 4;

  const f16* Qb = Q + ((size_t)(b * SEQ + q0) * NH + h) * HD;
  const f16* Kh = Kb + ((size_t)b * SEQ * NKV + kvh) * HD;
  const f16* Vh = VT + ((size_t)(b * NKV + kvh)) * HD * SEQ;

  const float KSC2 = 0.08838834764831845f * 1.4426950408889634f;
  f16x8 qf[4];
#pragma unroll
  for (int kd = 0; kd < 4; kd++) {
    qf[kd] = *reinterpret_cast<const f16x8*>(Qb + (size_t)ll * (NH * HD) + kd * 32 + lg * 8);
#pragma unroll
    for (int j = 0; j < 8; j++) qf[kd][j] = (f16)((float)qf[kd][j] * KSC2);
  }

  float m_ = -INFINITY;
  float l_ = 0.f;
  f32x4 o[8];
#pragma unroll
  for (int df = 0; df < 8; df++) o[df] = f32x4{0.f, 0.f, 0.f, 0.f};
  f32x4 sP[4];   // scores of tile i-1 (pending softmax+PV)

  const float THR = 11.5416f;  // 8 nats in log2 units

  auto stageK = [&](int bufi, int kt) {
#pragma unroll
    for (int rr = 0; rr < 2; rr++) {
      const int u = w * 128 + rr * 64 + lane;
      const int krow = u >> 4, klin = u & 15;
      const int kslot = klin ^ (krow & 7);
      const f16* ksrc = Kh + (size_t)(kt + krow) * (NKV * HD) + kslot * 8;
      __builtin_amdgcn_global_load_lds((const __attribute__((address_space(1))) void*)ksrc,
          (__attribute__((address_space(3))) void*)((char*)&Klds[bufi][0] + (size_t)u * 16), 16, 0, 0);
    }
  };
  auto stageV = [&](int bufi, int kt) {
#pragma unroll
    for (int rr = 0; rr < 2; rr++) {
      const int u = w * 128 + rr * 64 + lane;
      const int vrow = u >> 3, vlin = u & 7;
      const int vslot = vlin ^ (vrow & 7);
      const f16* vsrc = Vh + (size_t)vrow * SEQ + kt + vslot * 8;
      __builtin_amdgcn_global_load_lds((const __attribute__((address_space(1))) void*)vsrc,
          (__attribute__((address_space(3))) void*)((char*)&Vlds[bufi][0] + (size_t)u * 16), 16, 0, 0);
    }
  };

  // softmax + P-write + PV for the pending tile (scores in sP), V tile at Vt.
  auto processPrev = [&](const char* Vt) {
    float mx = sP[0][0];
#pragma unroll
    for (int nf = 0; nf < 4; nf++)
#pragma unroll
      for (int r = 0; r < 4; r++) mx = fmaxf(mx, sP[nf][r]);

    if (!__all((int)(mx <= m_ + THR))) {
      float mr = fmaxf(mx, __shfl_xor(mx, 16, 64));
      mr = fmaxf(mr, __shfl_xor(mr, 32, 64));
      const float mn = fmaxf(m_, mr);
      const float corrq = __builtin_amdgcn_exp2f(m_ - mn);
      m_ = mn;
      l_ *= corrq;
#pragma unroll
      for (int r = 0; r < 4; r++) {
        const float c = __shfl(corrq, (lane & 48) | (lg * 4 + r), 64);
#pragma unroll
        for (int df = 0; df < 8; df++) o[df][r] *= c;
      }
    }

    float rs = 0.f;
#pragma unroll
    for (int nf = 0; nf < 4; nf++)
#pragma unroll
      for (int r = 0; r < 4; r++) {
        const float p = __builtin_amdgcn_exp2f(sP[nf][r] - m_);
        sP[nf][r] = p;
        rs += p;
      }
    rs += __shfl_xor(rs, 16, 64);
    rs += __shfl_xor(rs, 32, 64);
    l_ += rs;

    char* Pw = (char*)&Plds[w][0];
#pragma unroll
    for (int nf = 0; nf < 4; nf++) {
      union { f16 h[4]; ushort4 u4; } pk;
#pragma unroll
      for (int r = 0; r < 4; r++) pk.h[r] = (f16)sP[nf][r];
      *reinterpret_cast<ushort4*>(Pw + ll * 128 + ((nf * 32 + lg * 8) ^ ((ll & 7) << 4))) = pk.u4;
    }

    f16x8 pf[2];
#pragma unroll
    for (int kf = 0; kf < 2; kf++)
      pf[kf] = *reinterpret_cast<const f16x8*>(Pw + ll * 128 + (((kf << 6) + (lg << 4)) ^ ((ll & 7) << 4)));

#pragma unroll
    for (int kf = 0; kf < 2; kf++)
#pragma unroll
      for (int df = 0; df < 8; df++) {
        const int row = df * 16 + ll;
        f16x8 vf = *reinterpret_cast<const f16x8*>(
            Vt + row * 128 + ((((kf << 2) + lg) ^ (row & 7)) << 4));
        o[df] = __builtin_amdgcn_mfma_f32_16x16x32_f16(pf[kf], vf, o[df], 0, 0, 0);
      }
  };

  stageK(0, 0);
  stageV(0, 0);

  const int NT = SEQ / 64;   // 32
  for (int i = 0; i < NT; i++) {
    // wait: K(i) + V(i-1) landed; V(i) (2 newest per-wave loads) may stay in flight.
    asm volatile("s_waitcnt vmcnt(2)" ::: "memory");
    __builtin_amdgcn_sched_barrier(0);
    __builtin_amdgcn_s_barrier();

    const char* Kt = (const char*)Klds[i & 1];
    // QK(i): S^T = K · Q^T ; lane: kv = nf*16+lg*4+r, q = ll (log2 domain, prescaled Q)
    f32x4 sN[4];
#pragma unroll
    for (int nf = 0; nf < 4; nf++) {
      f32x4 a = f32x4{0.f, 0.f, 0.f, 0.f};
#pragma unroll
      for (int kd = 0; kd < 4; kd++) {
        const int row = nf * 16 + ll;
        f16x8 kf = *reinterpret_cast<const f16x8*>(
            Kt + row * 256 + ((((kd << 2) + lg) ^ (row & 7)) << 4));
        a = __builtin_amdgcn_mfma_f32_16x16x32_f16(kf, qf[kd], a, 0, 0, 0);
      }
      sN[nf] = a;
    }

    // overlap: softmax + PV of tile i-1 (VALU+MFMA) interleaves with QK(i) completion
    if (i > 0) processPrev((const char*)Vlds[(i - 1) & 1]);

    __builtin_amdgcn_s_barrier();   // all waves done reading V(i-1) buffer
    if (i + 1 < NT) {
      stageK((i + 1) & 1, (i + 1) * 64);
      stageV((i + 1) & 1, (i + 1) * 64);   // V last: the 2 loads allowed to stay in flight
    }
#pragma unroll
    for (int nf = 0; nf < 4; nf++) sP[nf] = sN[nf];
  }

  // flush tile NT-1
  asm volatile("s_waitcnt vmcnt(0)" ::: "memory");
  __builtin_amdgcn_sched_barrier(0);
  __builtin_amdgcn_s_barrier();
  processPrev((const char*)Vlds[(NT - 1) & 1]);

  float inv[4];
#pragma unroll
  for (int r = 0; r < 4; r++) {
    const float lq = __shfl(l_, (lane & 48) | (lg * 4 + r), 64);
    inv[r] = 1.0f / lq;
  }
  f16* cb = ctx + ((size_t)(b * SEQ + q0) * NH + h) * HD;
#pragma unroll
  for (int df = 0; df < 8; df++)
#pragma unroll
    for (int r = 0; r < 4; r++)
      cb[(size_t)(lg * 4 + r) * (NH * HD) + df * 16 + ll] = (f16)(o[df][r] * inv[r]);
}

extern "C" void kernel_launch(void* const* d_in, const int* in_sizes, int n_in,
                              void* d_out, int out_size, void* d_ws, size_t ws_size,
                              hipStream_t stream) {
  (void)in_sizes; (void)n_in; (void)out_size;
  const float* x  = (const float*)d_in[0];
  const float* wq = (const float*)d_in[1];
  const float* wk = (const float*)d_in[2];
  const float* wv = (const float*)d_in[3];
  const float* wo = (const float*)d_in[4];
  float* out = (float*)d_out;

  const size_t SZ_X  = (size_t)MTOK * DMODEL * sizeof(f16);
  const size_t SZ_KV = (size_t)MTOK * NKV * HD * sizeof(f16);
  if (ws_size < 3 * SZ_X + 2 * SZ_KV) return;

  char* ws = (char*)d_ws;
  f16* xh  = (f16*)ws;                      // x f16; reused as ctx
  f16* wT  = (f16*)(ws + SZ_X);             // transposed weight (wq -> wk|wv -> wo)
  f16* Qb  = (f16*)(ws + 2 * SZ_X);
  f16* Kb  = (f16*)(ws + 3 * SZ_X);         // [B,S,NKV,HD]
  f16* VTb = (f16*)(ws + 3 * SZ_X + SZ_KV); // [B,NKV,HD,S] (right after Kb: MODE 3 relies on this)

  cvt_f32_f16_k<<<dim3(MTOK * DMODEL / 8 / 256), 256, 0, stream>>>(x, xh, MTOK * DMODEL / 8);

  transpose_cvt_k<<<dim3(DMODEL / 32, DMODEL / 32), 256, 0, stream>>>(wq, wT, DMODEL, DMODEL);
  gemm256_k<0><<<dim3((MTOK / 256) * (DMODEL / 256)), 512, 0, stream>>>(xh, wT, Qb, MTOK, DMODEL, DMODEL);

  // merged K|V projection: wT rows 0-1023 = wk^T, rows 1024-2047 = wv^T
  transpose_cvt_k<<<dim3(NKV * HD / 32, DMODEL / 32), 256, 0, stream>>>(wk, wT, DMODEL, NKV * HD);
  transpose_cvt_k<<<dim3(NKV * HD / 32, DMODEL / 32), 256, 0, stream>>>(wv, wT + (size_t)1024 * DMODEL, DMODEL, NKV * HD);
  gemm_bt_k<3><<<dim3((MTOK / 128) * (2048 / 128)), 256, 0, stream>>>(xh, wT, Kb, MTOK, 2048, DMODEL);

  attn_k5<<<dim3(BATCH * NKV * (SEQ / 32)), 512, 0, stream>>>(Qb, Kb, VTb, xh);

  transpose_cvt_k<<<dim3(DMODEL / 32, DMODEL / 32), 256, 0, stream>>>(wo, wT, DMODEL, DMODEL);
  gemm256_k<2><<<dim3((MTOK / 256) * (DMODEL / 256)), 512, 0, stream>>>(xh, wT, out, MTOK, DMODEL, DMODEL);
}

// Round 6
// 592.191 us; speedup vs baseline: 1.0855x; 1.0855x over previous
//
#include <hip/hip_runtime.h>
#include <math.h>

typedef _Float16 f16;
using f16x8 = __attribute__((ext_vector_type(8))) _Float16;
using f32x4 = __attribute__((ext_vector_type(4))) float;

#define BATCH 2
#define SEQ   2048
#define DMODEL 4096
#define NH    32
#define NKV   8
#define HD    128
#define MTOK  (BATCH*SEQ)

// ---------------- f32 -> f16 convert ----------------
__global__ __launch_bounds__(256) void cvt_f32_f16_k(const float* __restrict__ in,
                                                     f16* __restrict__ out, int n8) {
  int i = blockIdx.x * 256 + threadIdx.x;
  if (i >= n8) return;
  const float4* p = reinterpret_cast<const float4*>(in) + (size_t)i * 2;
  float4 a = p[0], b = p[1];
  f16x8 o = { (f16)a.x, (f16)a.y, (f16)a.z, (f16)a.w,
              (f16)b.x, (f16)b.y, (f16)b.z, (f16)b.w };
  reinterpret_cast<f16x8*>(out)[i] = o;
}

// ------------- w[K][N] f32 -> wT[N][K] f16 -------------
__global__ __launch_bounds__(256) void transpose_cvt_k(const float* __restrict__ w,
                                                       f16* __restrict__ wt, int Kd, int Nd) {
  __shared__ float tile[32][33];
  const int t = threadIdx.x;
  const int n0 = blockIdx.x * 32, k0 = blockIdx.y * 32;
  const int r = t >> 3, c4 = (t & 7) << 2;
  const float4 v = *reinterpret_cast<const float4*>(w + (size_t)(k0 + r) * Nd + n0 + c4);
  tile[r][c4 + 0] = v.x; tile[r][c4 + 1] = v.y; tile[r][c4 + 2] = v.z; tile[r][c4 + 3] = v.w;
  __syncthreads();
  union { f16 h[4]; ushort4 u4; } pk;
  pk.h[0] = (f16)tile[c4 + 0][r];
  pk.h[1] = (f16)tile[c4 + 1][r];
  pk.h[2] = (f16)tile[c4 + 2][r];
  pk.h[3] = (f16)tile[c4 + 3][r];
  *reinterpret_cast<ushort4*>(wt + (size_t)(n0 + r) * Kd + k0 + c4) = pk.u4;
}

// ------------- 128^2 GEMM. MODE 3: merged K|V projection (N=2048):
//   ncol<1024 -> K[B,S,NKV,HD] (row stride 1024); ncol>=1024 -> VT[B,NKV,HD,SEQ]
template<int MODE>
__global__ __launch_bounds__(256) void gemm_bt_k(const f16* __restrict__ A,
                                                 const f16* __restrict__ BT,
                                                 void* __restrict__ Cv,
                                                 int M, int N, int K) {
  __shared__ f16 Alds[128 * 64];
  __shared__ f16 Blds[128 * 64];
  const int t = threadIdx.x, lane = t & 63, w = t >> 6;
  const int nbn = N >> 7;
  const int nwg = gridDim.x;
  const int cpx = nwg >> 3;
  const int bid = blockIdx.x;
  const int swz = (bid & 7) * cpx + (bid >> 3);
  const int bm = swz / nbn, bn = swz % nbn;
  const size_t m0 = (size_t)bm << 7, n0 = (size_t)bn << 7;

  const int srow = t >> 3;
  const int sslot = t & 7;
  char* ldsAw = (char*)Alds + w * 1024;
  char* ldsBw = (char*)Blds + w * 1024;

  f32x4 acc[4][4];
#pragma unroll
  for (int i = 0; i < 4; i++)
#pragma unroll
    for (int j = 0; j < 4; j++) acc[i][j] = f32x4{0.f, 0.f, 0.f, 0.f};

  const int wr = (w >> 1) << 6, wc = (w & 1) << 6;
  const int ll = lane & 15, lg = lane >> 4;

  for (int kt = 0; kt < K; kt += 64) {
    __syncthreads();
#pragma unroll
    for (int p = 0; p < 4; p++) {
      const int row = srow + (p << 5);
      const int ssrc = (sslot ^ (row & 7)) << 3;
      const f16* gA = A + (m0 + row) * (size_t)K + kt + ssrc;
      __builtin_amdgcn_global_load_lds((const __attribute__((address_space(1))) void*)gA,
          (__attribute__((address_space(3))) void*)(ldsAw + p * 4096), 16, 0, 0);
      const f16* gB = BT + (n0 + row) * (size_t)K + kt + ssrc;
      __builtin_amdgcn_global_load_lds((const __attribute__((address_space(1))) void*)gB,
          (__attribute__((address_space(3))) void*)(ldsBw + p * 4096), 16, 0, 0);
    }
    __syncthreads();
#pragma unroll
    for (int kk = 0; kk < 2; kk++) {
      f16x8 af[4], bfr[4];
      const int slot = (kk << 2) + lg;
#pragma unroll
      for (int i = 0; i < 4; i++) {
        const int r = wr + (i << 4) + ll;
        af[i] = *reinterpret_cast<const f16x8*>((const char*)Alds + r * 128 + ((slot ^ (r & 7)) << 4));
      }
#pragma unroll
      for (int j = 0; j < 4; j++) {
        const int r = wc + (j << 4) + ll;
        bfr[j] = *reinterpret_cast<const f16x8*>((const char*)Blds + r * 128 + ((slot ^ (r & 7)) << 4));
      }
#pragma unroll
      for (int i = 0; i < 4; i++)
#pragma unroll
        for (int j = 0; j < 4; j++)
          acc[i][j] = __builtin_amdgcn_mfma_f32_16x16x32_f16(af[i], bfr[j], acc[i][j], 0, 0, 0);
    }
  }

#pragma unroll
  for (int i = 0; i < 4; i++) {
    const size_t mrow = m0 + wr + (i << 4) + (lg << 2);
#pragma unroll
    for (int j = 0; j < 4; j++) {
      const size_t ncol = n0 + wc + (j << 4) + ll;
      if (MODE == 0) {
        f16* C = (f16*)Cv;
#pragma unroll
        for (int r = 0; r < 4; r++) C[(mrow + r) * N + ncol] = (f16)acc[i][j][r];
      } else if (MODE == 2) {
        float* C = (float*)Cv;
#pragma unroll
        for (int r = 0; r < 4; r++) C[(mrow + r) * N + ncol] = acc[i][j][r];
      } else if (MODE == 3) {
        f16* Kc = (f16*)Cv;
        f16* Vt = (f16*)Cv + (size_t)MTOK * NKV * HD;   // VT sits right after K in ws
        if ((int)ncol < 1024) {
#pragma unroll
          for (int r = 0; r < 4; r++) Kc[(mrow + r) * 1024 + ncol] = (f16)acc[i][j][r];
        } else {
          const int nc = (int)ncol - 1024;
          const int kvh = nc >> 7, d = nc & 127;
          const int b = (int)(mrow >> 11), sc = (int)(mrow & 2047);
          union { f16 h[4]; ushort4 u4; } pk;
#pragma unroll
          for (int r = 0; r < 4; r++) pk.h[r] = (f16)acc[i][j][r];
          *reinterpret_cast<ushort4*>(Vt + (((size_t)(b * NKV + kvh) * HD + d) * SEQ + sc)) = pk.u4;
        }
      }
    }
  }
}

// ------------- 256^2 8-phase GEMM (T2+T3+T4+T5) for the two 4096^3 GEMMs -------------
template<int MODE>
__global__ __launch_bounds__(512, 2) void gemm256_k(const f16* __restrict__ A,
                                                    const f16* __restrict__ BT,
                                                    void* __restrict__ Cv,
                                                    int M, int N, int K) {
  __shared__ f16 lds[2 * 4 * 128 * 64];   // 128 KB
  char* ldsb = (char*)lds;

  const int t = threadIdx.x, lane = t & 63, w = t >> 6;
  const int wm = w >> 2, wn = w & 3;
  const int ll = lane & 15, lg = lane >> 4;
  const int nbn = N >> 8;
  const int nwg = gridDim.x, cpx = nwg >> 3, bid = blockIdx.x;
  const int swz = (bid & 7) * cpx + (bid >> 3);
  const int bm = swz / nbn, bn = swz % nbn;
  const size_t m0 = (size_t)bm << 8, n0 = (size_t)bn << 8;
  const int NT = K >> 6;

  auto stage = [&](int bufI, int unit, int ktS) {
    const f16* base = (unit < 2) ? (A + (m0 + (size_t)(unit & 1) * 128) * (size_t)K)
                                 : (BT + (n0 + (size_t)(unit & 1) * 128) * (size_t)K);
#pragma unroll
    for (int rr = 0; rr < 2; rr++) {
      const int u = t + rr * 512;
      const int row = u >> 3, lin = u & 7;
      const int slot = lin ^ (row & 7);
      const f16* src = base + (size_t)row * K + ktS + slot * 8;
      char* dst = ldsb + (size_t)(bufI * 4 + unit) * 16384 + (size_t)(w * 64 + rr * 512) * 16;
      __builtin_amdgcn_global_load_lds((const __attribute__((address_space(1))) void*)src,
          (__attribute__((address_space(3))) void*)dst, 16, 0, 0);
    }
  };

  f32x4 acc[8][4];
#pragma unroll
  for (int i = 0; i < 8; i++)
#pragma unroll
    for (int j = 0; j < 4; j++) acc[i][j] = f32x4{0.f, 0.f, 0.f, 0.f};

  f16x8 af[4][2];
  f16x8 bfr[2][2][2];

  stage(0, 0, 0); stage(0, 2, 0); stage(0, 3, 0); stage(0, 1, 0);
  stage(1, 0, 64); stage(1, 2, 64); stage(1, 3, 64);
  asm volatile("s_waitcnt vmcnt(6)" ::: "memory");
  __builtin_amdgcn_sched_barrier(0);
  __builtin_amdgcn_s_barrier();

#define PH(RBUF, RDA, RDB, SBUF, SUNIT, STILE, VM, MH, NHQ) do {                          \
    if ((RDA) >= 0) {                                                                     \
      const char* ab = ldsb + (size_t)((RBUF) * 4 + (RDA)) * 16384;                       \
      _Pragma("unroll") for (int mi = 0; mi < 4; mi++)                                    \
        _Pragma("unroll") for (int kk = 0; kk < 2; kk++)                                  \
          af[mi][kk] = *reinterpret_cast<const f16x8*>(ab + (mi * 32 + wm * 16 + ll) * 128\
                               + ((((kk << 2) + lg) ^ (ll & 7)) << 4));                   \
    }                                                                                     \
    if ((RDB) >= 0) {                                                                     \
      const char* bb = ldsb + (size_t)((RBUF) * 4 + 2 + (RDB)) * 16384;                   \
      _Pragma("unroll") for (int ni = 0; ni < 2; ni++)                                    \
        _Pragma("unroll") for (int kk = 0; kk < 2; kk++)                                  \
          bfr[RDB][ni][kk] = *reinterpret_cast<const f16x8*>(bb +                         \
                               (wn * 32 + ni * 16 + ll) * 128                             \
                               + ((((kk << 2) + lg) ^ (ll & 7)) << 4));                   \
    }                                                                                     \
    stage((SBUF), (SUNIT), ((STILE) & (NT - 1)) << 6);                                    \
    if (VM) { asm volatile("s_waitcnt vmcnt(6)" ::: "memory");                            \
              __builtin_amdgcn_sched_barrier(0); }                                        \
    __builtin_amdgcn_s_barrier();                                                         \
    asm volatile("s_waitcnt lgkmcnt(0)" ::: "memory");                                    \
    __builtin_amdgcn_sched_barrier(0);                                                    \
    __builtin_amdgcn_s_setprio(1);                                                        \
    _Pragma("unroll") for (int kk = 0; kk < 2; kk++)                                      \
      _Pragma("unroll") for (int mi = 0; mi < 4; mi++)                                    \
        _Pragma("unroll") for (int ni = 0; ni < 2; ni++)                                  \
          acc[(MH) * 4 + mi][(NHQ) * 2 + ni] = __builtin_amdgcn_mfma_f32_16x16x32_f16(    \
              af[mi][kk], bfr[NHQ][ni][kk], acc[(MH) * 4 + mi][(NHQ) * 2 + ni], 0, 0, 0); \
    __builtin_amdgcn_s_setprio(0);                                                        \
    __builtin_amdgcn_s_barrier();                                                         \
  } while (0)

  for (int tt = 0; tt < NT; tt += 2) {
    PH(0,  0,  0, 1, 1, tt + 1, false, 0, 0);
    PH(0, -1,  1, 0, 0, tt + 2, false, 0, 1);
    PH(0,  1, -1, 0, 2, tt + 2, false, 1, 0);
    PH(0, -1, -1, 0, 3, tt + 2, true , 1, 1);
    PH(1,  0,  0, 0, 1, tt + 2, false, 0, 0);
    PH(1, -1,  1, 1, 0, tt + 3, false, 0, 1);
    PH(1,  1, -1, 1, 2, tt + 3, false, 1, 0);
    PH(1, -1, -1, 1, 3, tt + 3, true , 1, 1);
  }
#undef PH

#pragma unroll
  for (int mh = 0; mh < 2; mh++)
#pragma unroll
    for (int mi = 0; mi < 4; mi++) {
      const size_t r0 = m0 + mh * 128 + mi * 32 + wm * 16 + lg * 4;
#pragma unroll
      for (int nh = 0; nh < 2; nh++)
#pragma unroll
        for (int ni = 0; ni < 2; ni++) {
          const size_t c = n0 + nh * 128 + wn * 32 + ni * 16 + ll;
          const f32x4 v = acc[mh * 4 + mi][nh * 2 + ni];
          if (MODE == 0) {
            f16* C = (f16*)Cv;
#pragma unroll
            for (int rr = 0; rr < 4; rr++) C[(r0 + rr) * N + c] = (f16)v[rr];
          } else {
            float* C = (float*)Cv;
#pragma unroll
            for (int rr = 0; rr < 4; rr++) C[(r0 + rr) * N + c] = v[rr];
          }
        }
    }
}

// ------------- flash attention v6: v5 pipeline, spill-free -------------
// No launch_bounds min (v5's (512,4) pinned VGPR=64 -> scratch spills, WRITE_SIZE 4x).
// Ping-pong score tiles sA/sB (statically named, no copy). Sync scheme identical to v5:
// stage-ahead-1, vmcnt(2) (V loads stay in flight across the barrier), raw s_barrier.
__global__ __launch_bounds__(512) void attn_k6(const f16* __restrict__ Q,
                                               const f16* __restrict__ Kb,
                                               const f16* __restrict__ VT,
                                               f16* __restrict__ ctx) {
  __shared__ f16 Klds[2][64 * 128];   // 16 KB x2
  __shared__ f16 Vlds[2][128 * 64];   // 16 KB x2
  __shared__ f16 Plds[8][16 * 64];    // 2 KB/wave (total 80 KB -> 2 blocks/CU)

  const int t = threadIdx.x, lane = t & 63, w = t >> 6;
  const int bid = blockIdx.x;
  const int swz = (bid & 7) * 128 + (bid >> 3);
  const int qt = swz & 63, kvh = (swz >> 6) & 7, b = swz >> 9;
  const int h = kvh * 4 + (w & 3);
  const int q0 = qt * 32 + (w >> 2) * 16;
  const int ll = lane & 15, lg = lane >> 4;

  const f16* Qb = Q + ((size_t)(b * SEQ + q0) * NH + h) * HD;
  const f16* Kh = Kb + ((size_t)b * SEQ * NKV + kvh) * HD;
  const f16* Vh = VT + ((size_t)(b * NKV + kvh)) * HD * SEQ;

  const float KSC2 = 0.08838834764831845f * 1.4426950408889634f;
  f16x8 qf[4];
#pragma unroll
  for (int kd = 0; kd < 4; kd++) {
    qf[kd] = *reinterpret_cast<const f16x8*>(Qb + (size_t)ll * (NH * HD) + kd * 32 + lg * 8);
#pragma unroll
    for (int j = 0; j < 8; j++) qf[kd][j] = (f16)((float)qf[kd][j] * KSC2);
  }

  float m_ = -INFINITY;
  float l_ = 0.f;
  f32x4 o[8];
#pragma unroll
  for (int df = 0; df < 8; df++) o[df] = f32x4{0.f, 0.f, 0.f, 0.f};
  f32x4 sA[4], sB[4];

  const float THR = 11.5416f;  // 8 nats in log2 units

  auto stageK = [&](int bufi, int kt) {
#pragma unroll
    for (int rr = 0; rr < 2; rr++) {
      const int u = w * 128 + rr * 64 + lane;
      const int krow = u >> 4, klin = u & 15;
      const int kslot = klin ^ (krow & 7);
      const f16* ksrc = Kh + (size_t)(kt + krow) * (NKV * HD) + kslot * 8;
      __builtin_amdgcn_global_load_lds((const __attribute__((address_space(1))) void*)ksrc,
          (__attribute__((address_space(3))) void*)((char*)&Klds[bufi][0] + (size_t)u * 16), 16, 0, 0);
    }
  };
  auto stageV = [&](int bufi, int kt) {
#pragma unroll
    for (int rr = 0; rr < 2; rr++) {
      const int u = w * 128 + rr * 64 + lane;
      const int vrow = u >> 3, vlin = u & 7;
      const int vslot = vlin ^ (vrow & 7);
      const f16* vsrc = Vh + (size_t)vrow * SEQ + kt + vslot * 8;
      __builtin_amdgcn_global_load_lds((const __attribute__((address_space(1))) void*)vsrc,
          (__attribute__((address_space(3))) void*)((char*)&Vlds[bufi][0] + (size_t)u * 16), 16, 0, 0);
    }
  };

  // QK for tile i -> dst (S^T: lane kv = nf*16+lg*4+r, q = ll, log2 domain)
  auto qk = [&](int i, f32x4* dst) {
    const char* Kt = (const char*)Klds[i & 1];
#pragma unroll
    for (int nf = 0; nf < 4; nf++) {
      f32x4 a = f32x4{0.f, 0.f, 0.f, 0.f};
#pragma unroll
      for (int kd = 0; kd < 4; kd++) {
        const int row = nf * 16 + ll;
        f16x8 kf = *reinterpret_cast<const f16x8*>(
            Kt + row * 256 + ((((kd << 2) + lg) ^ (row & 7)) << 4));
        a = __builtin_amdgcn_mfma_f32_16x16x32_f16(kf, qf[kd], a, 0, 0, 0);
      }
      dst[nf] = a;
    }
  };

  // softmax + P-write + PV for pending tile (scores sP), V tile at Vt.
  auto processPrev = [&](f32x4* sP, const char* Vt) {
    float mx = sP[0][0];
#pragma unroll
    for (int nf = 0; nf < 4; nf++)
#pragma unroll
      for (int r = 0; r < 4; r++) mx = fmaxf(mx, sP[nf][r]);

    if (!__all((int)(mx <= m_ + THR))) {
      float mr = fmaxf(mx, __shfl_xor(mx, 16, 64));
      mr = fmaxf(mr, __shfl_xor(mr, 32, 64));
      const float mn = fmaxf(m_, mr);
      const float corrq = __builtin_amdgcn_exp2f(m_ - mn);
      m_ = mn;
      l_ *= corrq;
#pragma unroll
      for (int r = 0; r < 4; r++) {
        const float c = __shfl(corrq, (lane & 48) | (lg * 4 + r), 64);
#pragma unroll
        for (int df = 0; df < 8; df++) o[df][r] *= c;
      }
    }

    float rs = 0.f;
#pragma unroll
    for (int nf = 0; nf < 4; nf++)
#pragma unroll
      for (int r = 0; r < 4; r++) {
        const float p = __builtin_amdgcn_exp2f(sP[nf][r] - m_);
        sP[nf][r] = p;
        rs += p;
      }
    rs += __shfl_xor(rs, 16, 64);
    rs += __shfl_xor(rs, 32, 64);
    l_ += rs;

    char* Pw = (char*)&Plds[w][0];
#pragma unroll
    for (int nf = 0; nf < 4; nf++) {
      union { f16 h[4]; ushort4 u4; } pk;
#pragma unroll
      for (int r = 0; r < 4; r++) pk.h[r] = (f16)sP[nf][r];
      *reinterpret_cast<ushort4*>(Pw + ll * 128 + ((nf * 32 + lg * 8) ^ ((ll & 7) << 4))) = pk.u4;
    }

    f16x8 pf[2];
#pragma unroll
    for (int kf = 0; kf < 2; kf++)
      pf[kf] = *reinterpret_cast<const f16x8*>(Pw + ll * 128 + (((kf << 6) + (lg << 4)) ^ ((ll & 7) << 4)));

#pragma unroll
    for (int kf = 0; kf < 2; kf++)
#pragma unroll
      for (int df = 0; df < 8; df++) {
        const int row = df * 16 + ll;
        f16x8 vf = *reinterpret_cast<const f16x8*>(
            Vt + row * 128 + ((((kf << 2) + lg) ^ (row & 7)) << 4));
        o[df] = __builtin_amdgcn_mfma_f32_16x16x32_f16(pf[kf], vf, o[df], 0, 0, 0);
      }
  };

  const int NT = SEQ / 64;   // 32 (even)

  // ITER body: sync; QK(i)->CUR; process PREV (tile i-1); barrier; stage tile i+1.
#define AITER(I, CUR, PREV, DO_PREV) do {                                   \
    asm volatile("s_waitcnt vmcnt(2)" ::: "memory");                        \
    __builtin_amdgcn_sched_barrier(0);                                      \
    __builtin_amdgcn_s_barrier();                                           \
    qk((I), (CUR));                                                         \
    if (DO_PREV) processPrev((PREV), (const char*)Vlds[((I) - 1) & 1]);     \
    __builtin_amdgcn_s_barrier();                                           \
    if ((I) + 1 < NT) { stageK(((I) + 1) & 1, ((I) + 1) * 64);              \
                        stageV(((I) + 1) & 1, ((I) + 1) * 64); }            \
  } while (0)

  stageK(0, 0);
  stageV(0, 0);

  AITER(0, sA, sB, false);
  AITER(1, sB, sA, true);
  for (int i = 2; i < NT; i += 2) {
    AITER(i, sA, sB, true);
    AITER(i + 1, sB, sA, true);
  }
#undef AITER

  // flush tile NT-1 (odd -> sB)
  asm volatile("s_waitcnt vmcnt(0)" ::: "memory");
  __builtin_amdgcn_sched_barrier(0);
  __builtin_amdgcn_s_barrier();
  processPrev(sB, (const char*)Vlds[(NT - 1) & 1]);

  float inv[4];
#pragma unroll
  for (int r = 0; r < 4; r++) {
    const float lq = __shfl(l_, (lane & 48) | (lg * 4 + r), 64);
    inv[r] = 1.0f / lq;
  }
  f16* cb = ctx + ((size_t)(b * SEQ + q0) * NH + h) * HD;
#pragma unroll
  for (int df = 0; df < 8; df++)
#pragma unroll
    for (int r = 0; r < 4; r++)
      cb[(size_t)(lg * 4 + r) * (NH * HD) + df * 16 + ll] = (f16)(o[df][r] * inv[r]);
}

extern "C" void kernel_launch(void* const* d_in, const int* in_sizes, int n_in,
                              void* d_out, int out_size, void* d_ws, size_t ws_size,
                              hipStream_t stream) {
  (void)in_sizes; (void)n_in; (void)out_size;
  const float* x  = (const float*)d_in[0];
  const float* wq = (const float*)d_in[1];
  const float* wk = (const float*)d_in[2];
  const float* wv = (const float*)d_in[3];
  const float* wo = (const float*)d_in[4];
  float* out = (float*)d_out;

  const size_t SZ_X  = (size_t)MTOK * DMODEL * sizeof(f16);
  const size_t SZ_KV = (size_t)MTOK * NKV * HD * sizeof(f16);
  if (ws_size < 3 * SZ_X + 2 * SZ_KV) return;

  char* ws = (char*)d_ws;
  f16* xh  = (f16*)ws;                      // x f16; reused as ctx
  f16* wT  = (f16*)(ws + SZ_X);             // transposed weight (wq -> wk|wv -> wo)
  f16* Qb  = (f16*)(ws + 2 * SZ_X);
  f16* Kb  = (f16*)(ws + 3 * SZ_X);         // [B,S,NKV,HD]
  f16* VTb = (f16*)(ws + 3 * SZ_X + SZ_KV); // [B,NKV,HD,S] (right after Kb: MODE 3 relies on this)

  cvt_f32_f16_k<<<dim3(MTOK * DMODEL / 8 / 256), 256, 0, stream>>>(x, xh, MTOK * DMODEL / 8);

  transpose_cvt_k<<<dim3(DMODEL / 32, DMODEL / 32), 256, 0, stream>>>(wq, wT, DMODEL, DMODEL);
  gemm256_k<0><<<dim3((MTOK / 256) * (DMODEL / 256)), 512, 0, stream>>>(xh, wT, Qb, MTOK, DMODEL, DMODEL);

  // merged K|V projection: wT rows 0-1023 = wk^T, rows 1024-2047 = wv^T
  transpose_cvt_k<<<dim3(NKV * HD / 32, DMODEL / 32), 256, 0, stream>>>(wk, wT, DMODEL, NKV * HD);
  transpose_cvt_k<<<dim3(NKV * HD / 32, DMODEL / 32), 256, 0, stream>>>(wv, wT + (size_t)1024 * DMODEL, DMODEL, NKV * HD);
  gemm_bt_k<3><<<dim3((MTOK / 128) * (2048 / 128)), 256, 0, stream>>>(xh, wT, Kb, MTOK, 2048, DMODEL);

  attn_k6<<<dim3(BATCH * NKV * (SEQ / 32)), 512, 0, stream>>>(Qb, Kb, VTb, xh);

  transpose_cvt_k<<<dim3(DMODEL / 32, DMODEL / 32), 256, 0, stream>>>(wo, wT, DMODEL, DMODEL);
  gemm256_k<2><<<dim3((MTOK / 256) * (DMODEL / 256)), 512, 0, stream>>>(xh, wT, out, MTOK, DMODEL, DMODEL);
}

// Round 7
// 551.447 us; speedup vs baseline: 1.1656x; 1.0739x over previous
//
#include <hip/hip_runtime.h>
#include <math.h>

typedef _Float16 f16;
using f16x8 = __attribute__((ext_vector_type(8))) _Float16;
using f32x4 = __attribute__((ext_vector_type(4))) float;

#define BATCH 2
#define SEQ   2048
#define DMODEL 4096
#define NH    32
#define NKV   8
#define HD    128
#define MTOK  (BATCH*SEQ)

// ---------------- f32 -> f16 convert ----------------
__global__ __launch_bounds__(256) void cvt_f32_f16_k(const float* __restrict__ in,
                                                     f16* __restrict__ out, int n8) {
  int i = blockIdx.x * 256 + threadIdx.x;
  if (i >= n8) return;
  const float4* p = reinterpret_cast<const float4*>(in) + (size_t)i * 2;
  float4 a = p[0], b = p[1];
  f16x8 o = { (f16)a.x, (f16)a.y, (f16)a.z, (f16)a.w,
              (f16)b.x, (f16)b.y, (f16)b.z, (f16)b.w };
  reinterpret_cast<f16x8*>(out)[i] = o;
}

// ------------- w[K][N] f32 -> wT[N][K] f16 (optionally scaled: folds softmax scale into wq) -------------
__global__ __launch_bounds__(256) void transpose_cvt_k(const float* __restrict__ w,
                                                       f16* __restrict__ wt, int Kd, int Nd,
                                                       float scale) {
  __shared__ float tile[32][33];
  const int t = threadIdx.x;
  const int n0 = blockIdx.x * 32, k0 = blockIdx.y * 32;
  const int r = t >> 3, c4 = (t & 7) << 2;
  const float4 v = *reinterpret_cast<const float4*>(w + (size_t)(k0 + r) * Nd + n0 + c4);
  tile[r][c4 + 0] = v.x; tile[r][c4 + 1] = v.y; tile[r][c4 + 2] = v.z; tile[r][c4 + 3] = v.w;
  __syncthreads();
  union { f16 h[4]; ushort4 u4; } pk;
  pk.h[0] = (f16)(tile[c4 + 0][r] * scale);
  pk.h[1] = (f16)(tile[c4 + 1][r] * scale);
  pk.h[2] = (f16)(tile[c4 + 2][r] * scale);
  pk.h[3] = (f16)(tile[c4 + 3][r] * scale);
  *reinterpret_cast<ushort4*>(wt + (size_t)(n0 + r) * Kd + k0 + c4) = pk.u4;
}

// ------------- 128^2 GEMM. MODE 3: merged K|V projection (N=2048):
//   ncol<1024 -> K[B,S,NKV,HD] (row stride 1024); ncol>=1024 -> VT[B,NKV,HD,SEQ]
template<int MODE>
__global__ __launch_bounds__(256) void gemm_bt_k(const f16* __restrict__ A,
                                                 const f16* __restrict__ BT,
                                                 void* __restrict__ Cv,
                                                 int M, int N, int K) {
  __shared__ f16 Alds[128 * 64];
  __shared__ f16 Blds[128 * 64];
  const int t = threadIdx.x, lane = t & 63, w = t >> 6;
  const int nbn = N >> 7;
  const int nwg = gridDim.x;
  const int cpx = nwg >> 3;
  const int bid = blockIdx.x;
  const int swz = (bid & 7) * cpx + (bid >> 3);
  const int bm = swz / nbn, bn = swz % nbn;
  const size_t m0 = (size_t)bm << 7, n0 = (size_t)bn << 7;

  const int srow = t >> 3;
  const int sslot = t & 7;
  char* ldsAw = (char*)Alds + w * 1024;
  char* ldsBw = (char*)Blds + w * 1024;

  f32x4 acc[4][4];
#pragma unroll
  for (int i = 0; i < 4; i++)
#pragma unroll
    for (int j = 0; j < 4; j++) acc[i][j] = f32x4{0.f, 0.f, 0.f, 0.f};

  const int wr = (w >> 1) << 6, wc = (w & 1) << 6;
  const int ll = lane & 15, lg = lane >> 4;

  for (int kt = 0; kt < K; kt += 64) {
    __syncthreads();
#pragma unroll
    for (int p = 0; p < 4; p++) {
      const int row = srow + (p << 5);
      const int ssrc = (sslot ^ (row & 7)) << 3;
      const f16* gA = A + (m0 + row) * (size_t)K + kt + ssrc;
      __builtin_amdgcn_global_load_lds((const __attribute__((address_space(1))) void*)gA,
          (__attribute__((address_space(3))) void*)(ldsAw + p * 4096), 16, 0, 0);
      const f16* gB = BT + (n0 + row) * (size_t)K + kt + ssrc;
      __builtin_amdgcn_global_load_lds((const __attribute__((address_space(1))) void*)gB,
          (__attribute__((address_space(3))) void*)(ldsBw + p * 4096), 16, 0, 0);
    }
    __syncthreads();
#pragma unroll
    for (int kk = 0; kk < 2; kk++) {
      f16x8 af[4], bfr[4];
      const int slot = (kk << 2) + lg;
#pragma unroll
      for (int i = 0; i < 4; i++) {
        const int r = wr + (i << 4) + ll;
        af[i] = *reinterpret_cast<const f16x8*>((const char*)Alds + r * 128 + ((slot ^ (r & 7)) << 4));
      }
#pragma unroll
      for (int j = 0; j < 4; j++) {
        const int r = wc + (j << 4) + ll;
        bfr[j] = *reinterpret_cast<const f16x8*>((const char*)Blds + r * 128 + ((slot ^ (r & 7)) << 4));
      }
#pragma unroll
      for (int i = 0; i < 4; i++)
#pragma unroll
        for (int j = 0; j < 4; j++)
          acc[i][j] = __builtin_amdgcn_mfma_f32_16x16x32_f16(af[i], bfr[j], acc[i][j], 0, 0, 0);
    }
  }

#pragma unroll
  for (int i = 0; i < 4; i++) {
    const size_t mrow = m0 + wr + (i << 4) + (lg << 2);
#pragma unroll
    for (int j = 0; j < 4; j++) {
      const size_t ncol = n0 + wc + (j << 4) + ll;
      if (MODE == 0) {
        f16* C = (f16*)Cv;
#pragma unroll
        for (int r = 0; r < 4; r++) C[(mrow + r) * N + ncol] = (f16)acc[i][j][r];
      } else if (MODE == 2) {
        float* C = (float*)Cv;
#pragma unroll
        for (int r = 0; r < 4; r++) C[(mrow + r) * N + ncol] = acc[i][j][r];
      } else if (MODE == 3) {
        f16* Kc = (f16*)Cv;
        f16* Vt = (f16*)Cv + (size_t)MTOK * NKV * HD;   // VT sits right after K in ws
        if ((int)ncol < 1024) {
#pragma unroll
          for (int r = 0; r < 4; r++) Kc[(mrow + r) * 1024 + ncol] = (f16)acc[i][j][r];
        } else {
          const int nc = (int)ncol - 1024;
          const int kvh = nc >> 7, d = nc & 127;
          const int b = (int)(mrow >> 11), sc = (int)(mrow & 2047);
          union { f16 h[4]; ushort4 u4; } pk;
#pragma unroll
          for (int r = 0; r < 4; r++) pk.h[r] = (f16)acc[i][j][r];
          *reinterpret_cast<ushort4*>(Vt + (((size_t)(b * NKV + kvh) * HD + d) * SEQ + sc)) = pk.u4;
        }
      }
    }
  }
}

// ------------- 256^2 8-phase GEMM (T2+T3+T4+T5) for the two 4096^3 GEMMs -------------
template<int MODE>
__global__ __launch_bounds__(512, 2) void gemm256_k(const f16* __restrict__ A,
                                                    const f16* __restrict__ BT,
                                                    void* __restrict__ Cv,
                                                    int M, int N, int K) {
  __shared__ f16 lds[2 * 4 * 128 * 64];   // 128 KB
  char* ldsb = (char*)lds;

  const int t = threadIdx.x, lane = t & 63, w = t >> 6;
  const int wm = w >> 2, wn = w & 3;
  const int ll = lane & 15, lg = lane >> 4;
  const int nbn = N >> 8;
  const int nwg = gridDim.x, cpx = nwg >> 3, bid = blockIdx.x;
  const int swz = (bid & 7) * cpx + (bid >> 3);
  const int bm = swz / nbn, bn = swz % nbn;
  const size_t m0 = (size_t)bm << 8, n0 = (size_t)bn << 8;
  const int NT = K >> 6;

  auto stage = [&](int bufI, int unit, int ktS) {
    const f16* base = (unit < 2) ? (A + (m0 + (size_t)(unit & 1) * 128) * (size_t)K)
                                 : (BT + (n0 + (size_t)(unit & 1) * 128) * (size_t)K);
#pragma unroll
    for (int rr = 0; rr < 2; rr++) {
      const int u = t + rr * 512;
      const int row = u >> 3, lin = u & 7;
      const int slot = lin ^ (row & 7);
      const f16* src = base + (size_t)row * K + ktS + slot * 8;
      char* dst = ldsb + (size_t)(bufI * 4 + unit) * 16384 + (size_t)(w * 64 + rr * 512) * 16;
      __builtin_amdgcn_global_load_lds((const __attribute__((address_space(1))) void*)src,
          (__attribute__((address_space(3))) void*)dst, 16, 0, 0);
    }
  };

  f32x4 acc[8][4];
#pragma unroll
  for (int i = 0; i < 8; i++)
#pragma unroll
    for (int j = 0; j < 4; j++) acc[i][j] = f32x4{0.f, 0.f, 0.f, 0.f};

  f16x8 af[4][2];
  f16x8 bfr[2][2][2];

  stage(0, 0, 0); stage(0, 2, 0); stage(0, 3, 0); stage(0, 1, 0);
  stage(1, 0, 64); stage(1, 2, 64); stage(1, 3, 64);
  asm volatile("s_waitcnt vmcnt(6)" ::: "memory");
  __builtin_amdgcn_sched_barrier(0);
  __builtin_amdgcn_s_barrier();

#define PH(RBUF, RDA, RDB, SBUF, SUNIT, STILE, VM, MH, NHQ) do {                          \
    if ((RDA) >= 0) {                                                                     \
      const char* ab = ldsb + (size_t)((RBUF) * 4 + (RDA)) * 16384;                       \
      _Pragma("unroll") for (int mi = 0; mi < 4; mi++)                                    \
        _Pragma("unroll") for (int kk = 0; kk < 2; kk++)                                  \
          af[mi][kk] = *reinterpret_cast<const f16x8*>(ab + (mi * 32 + wm * 16 + ll) * 128\
                               + ((((kk << 2) + lg) ^ (ll & 7)) << 4));                   \
    }                                                                                     \
    if ((RDB) >= 0) {                                                                     \
      const char* bb = ldsb + (size_t)((RBUF) * 4 + 2 + (RDB)) * 16384;                   \
      _Pragma("unroll") for (int ni = 0; ni < 2; ni++)                                    \
        _Pragma("unroll") for (int kk = 0; kk < 2; kk++)                                  \
          bfr[RDB][ni][kk] = *reinterpret_cast<const f16x8*>(bb +                         \
                               (wn * 32 + ni * 16 + ll) * 128                             \
                               + ((((kk << 2) + lg) ^ (ll & 7)) << 4));                   \
    }                                                                                     \
    stage((SBUF), (SUNIT), ((STILE) & (NT - 1)) << 6);                                    \
    if (VM) { asm volatile("s_waitcnt vmcnt(6)" ::: "memory");                            \
              __builtin_amdgcn_sched_barrier(0); }                                        \
    __builtin_amdgcn_s_barrier();                                                         \
    asm volatile("s_waitcnt lgkmcnt(0)" ::: "memory");                                    \
    __builtin_amdgcn_sched_barrier(0);                                                    \
    __builtin_amdgcn_s_setprio(1);                                                        \
    _Pragma("unroll") for (int kk = 0; kk < 2; kk++)                                      \
      _Pragma("unroll") for (int mi = 0; mi < 4; mi++)                                    \
        _Pragma("unroll") for (int ni = 0; ni < 2; ni++)                                  \
          acc[(MH) * 4 + mi][(NHQ) * 2 + ni] = __builtin_amdgcn_mfma_f32_16x16x32_f16(    \
              af[mi][kk], bfr[NHQ][ni][kk], acc[(MH) * 4 + mi][(NHQ) * 2 + ni], 0, 0, 0); \
    __builtin_amdgcn_s_setprio(0);                                                        \
    __builtin_amdgcn_s_barrier();                                                         \
  } while (0)

  for (int tt = 0; tt < NT; tt += 2) {
    PH(0,  0,  0, 1, 1, tt + 1, false, 0, 0);
    PH(0, -1,  1, 0, 0, tt + 2, false, 0, 1);
    PH(0,  1, -1, 0, 2, tt + 2, false, 1, 0);
    PH(0, -1, -1, 0, 3, tt + 2, true , 1, 1);
    PH(1,  0,  0, 0, 1, tt + 2, false, 0, 0);
    PH(1, -1,  1, 1, 0, tt + 3, false, 0, 1);
    PH(1,  1, -1, 1, 2, tt + 3, false, 1, 0);
    PH(1, -1, -1, 1, 3, tt + 3, true , 1, 1);
  }
#undef PH

#pragma unroll
  for (int mh = 0; mh < 2; mh++)
#pragma unroll
    for (int mi = 0; mi < 4; mi++) {
      const size_t r0 = m0 + mh * 128 + mi * 32 + wm * 16 + lg * 4;
#pragma unroll
      for (int nh = 0; nh < 2; nh++)
#pragma unroll
        for (int ni = 0; ni < 2; ni++) {
          const size_t c = n0 + nh * 128 + wn * 32 + ni * 16 + ll;
          const f32x4 v = acc[mh * 4 + mi][nh * 2 + ni];
          if (MODE == 0) {
            f16* C = (f16*)Cv;
#pragma unroll
            for (int rr = 0; rr < 4; rr++) C[(r0 + rr) * N + c] = (f16)v[rr];
          } else {
            float* C = (float*)Cv;
#pragma unroll
            for (int rr = 0; rr < 4; rr++) C[(r0 + rr) * N + c] = v[rr];
          }
        }
    }
}

// ------------- flash attention v7 = v4 (proven 186 us), Q prescale folded into wq -------------
// 8 waves = 4 heads x 2 q-subtiles; swapped QK^T (S^T = K*Q^T), lane-local softmax;
// single __syncthreads per tile; stage-ahead-1 double buffer.
__global__ __launch_bounds__(512) void attn_k7(const f16* __restrict__ Q,
                                               const f16* __restrict__ Kb,
                                               const f16* __restrict__ VT,
                                               f16* __restrict__ ctx) {
  __shared__ f16 Klds[2][64 * 128];   // 16 KB x2
  __shared__ f16 Vlds[2][128 * 64];   // 16 KB x2
  __shared__ f16 Plds[8][16 * 64];    // 2 KB/wave (total 80 KB)

  const int t = threadIdx.x, lane = t & 63, w = t >> 6;
  const int bid = blockIdx.x;
  const int swz = (bid & 7) * 128 + (bid >> 3);
  const int qt = swz & 63, kvh = (swz >> 6) & 7, b = swz >> 9;
  const int h = kvh * 4 + (w & 3);
  const int q0 = qt * 32 + (w >> 2) * 16;
  const int ll = lane & 15, lg = lane >> 4;

  const f16* Qb = Q + ((size_t)(b * SEQ + q0) * NH + h) * HD;
  const f16* Kh = Kb + ((size_t)b * SEQ * NKV + kvh) * HD;
  const f16* Vh = VT + ((size_t)(b * NKV + kvh)) * HD * SEQ;

  // Q fragments (MFMA B operand: col=q=ll, k = kd*32+lg*8+j). Already prescaled via wq.
  f16x8 qf[4];
#pragma unroll
  for (int kd = 0; kd < 4; kd++)
    qf[kd] = *reinterpret_cast<const f16x8*>(Qb + (size_t)ll * (NH * HD) + kd * 32 + lg * 8);

  float m_ = -INFINITY;   // running max for q = ll (log2 domain)
  float l_ = 0.f;         // running sum for q = ll
  f32x4 o[8];
#pragma unroll
  for (int df = 0; df < 8; df++) o[df] = f32x4{0.f, 0.f, 0.f, 0.f};

  const float THR = 11.5416f;  // 8 nats in log2 units

  auto stage = [&](int bufi, int kt) {
#pragma unroll
    for (int rr = 0; rr < 2; rr++) {
      const int u = w * 128 + rr * 64 + lane;
      const int krow = u >> 4, klin = u & 15;
      const int kslot = klin ^ (krow & 7);
      const f16* ksrc = Kh + (size_t)(kt + krow) * (NKV * HD) + kslot * 8;
      __builtin_amdgcn_global_load_lds((const __attribute__((address_space(1))) void*)ksrc,
          (__attribute__((address_space(3))) void*)((char*)&Klds[bufi][0] + (size_t)u * 16), 16, 0, 0);
      const int vrow = u >> 3, vlin = u & 7;
      const int vslot = vlin ^ (vrow & 7);
      const f16* vsrc = Vh + (size_t)vrow * SEQ + kt + vslot * 8;
      __builtin_amdgcn_global_load_lds((const __attribute__((address_space(1))) void*)vsrc,
          (__attribute__((address_space(3))) void*)((char*)&Vlds[bufi][0] + (size_t)u * 16), 16, 0, 0);
    }
  };

  stage(0, 0);
  __syncthreads();

  for (int kt = 0; kt < SEQ; kt += 64) {
    const int buf = (kt >> 6) & 1;
    if (kt + 64 < SEQ) stage(buf ^ 1, kt + 64);

    const char* Kt = (const char*)Klds[buf];
    const char* Vt = (const char*)Vlds[buf];

    // S^T = K @ Q^T : lane: kv = nf*16+lg*4+r, q = ll (log2 domain)
    f32x4 s[4];
#pragma unroll
    for (int nf = 0; nf < 4; nf++) {
      f32x4 a = f32x4{0.f, 0.f, 0.f, 0.f};
#pragma unroll
      for (int kd = 0; kd < 4; kd++) {
        const int row = nf * 16 + ll;
        f16x8 kf = *reinterpret_cast<const f16x8*>(
            Kt + row * 256 + ((((kd << 2) + lg) ^ (row & 7)) << 4));
        a = __builtin_amdgcn_mfma_f32_16x16x32_f16(kf, qf[kd], a, 0, 0, 0);
      }
      s[nf] = a;
    }

    // lane-local softmax for column q = ll (16 kv values per lane).
    float mx = s[0][0];
#pragma unroll
    for (int nf = 0; nf < 4; nf++)
#pragma unroll
      for (int r = 0; r < 4; r++) mx = fmaxf(mx, s[nf][r]);

    if (!__all((int)(mx <= m_ + THR))) {
      float mr = fmaxf(mx, __shfl_xor(mx, 16, 64));
      mr = fmaxf(mr, __shfl_xor(mr, 32, 64));
      const float mn = fmaxf(m_, mr);
      const float corrq = __builtin_amdgcn_exp2f(m_ - mn);
      m_ = mn;
      l_ *= corrq;
#pragma unroll
      for (int r = 0; r < 4; r++) {
        const float c = __shfl(corrq, (lane & 48) | (lg * 4 + r), 64);
#pragma unroll
        for (int df = 0; df < 8; df++) o[df][r] *= c;
      }
    }

    float rs = 0.f;
#pragma unroll
    for (int nf = 0; nf < 4; nf++)
#pragma unroll
      for (int r = 0; r < 4; r++) {
        const float p = __builtin_amdgcn_exp2f(s[nf][r] - m_);
        s[nf][r] = p;
        rs += p;
      }
    rs += __shfl_xor(rs, 16, 64);
    rs += __shfl_xor(rs, 32, 64);
    l_ += rs;

    // P row-major [16 q][64 kv] f16, XOR-swizzled; lane writes its own row q=ll.
    char* Pw = (char*)&Plds[w][0];
#pragma unroll
    for (int nf = 0; nf < 4; nf++) {
      union { f16 h[4]; ushort4 u4; } pk;
#pragma unroll
      for (int r = 0; r < 4; r++) pk.h[r] = (f16)s[nf][r];
      *reinterpret_cast<ushort4*>(Pw + ll * 128 + ((nf * 32 + lg * 8) ^ ((ll & 7) << 4))) = pk.u4;
    }

    // PV A-frag: P[q=ll][kv = kf*32 + lg*8 + j]
    f16x8 pf[2];
#pragma unroll
    for (int kf = 0; kf < 2; kf++)
      pf[kf] = *reinterpret_cast<const f16x8*>(Pw + ll * 128 + (((kf << 6) + (lg << 4)) ^ ((ll & 7) << 4)));

    // O += P @ V
#pragma unroll
    for (int kf = 0; kf < 2; kf++)
#pragma unroll
      for (int df = 0; df < 8; df++) {
        const int row = df * 16 + ll;
        f16x8 vf = *reinterpret_cast<const f16x8*>(
            Vt + row * 128 + ((((kf << 2) + lg) ^ (row & 7)) << 4));
        o[df] = __builtin_amdgcn_mfma_f32_16x16x32_f16(pf[kf], vf, o[df], 0, 0, 0);
      }

    __syncthreads();
  }

  float inv[4];
#pragma unroll
  for (int r = 0; r < 4; r++) {
    const float lq = __shfl(l_, (lane & 48) | (lg * 4 + r), 64);
    inv[r] = 1.0f / lq;
  }
  f16* cb = ctx + ((size_t)(b * SEQ + q0) * NH + h) * HD;
#pragma unroll
  for (int df = 0; df < 8; df++)
#pragma unroll
    for (int r = 0; r < 4; r++)
      cb[(size_t)(lg * 4 + r) * (NH * HD) + df * 16 + ll] = (f16)(o[df][r] * inv[r]);
}

extern "C" void kernel_launch(void* const* d_in, const int* in_sizes, int n_in,
                              void* d_out, int out_size, void* d_ws, size_t ws_size,
                              hipStream_t stream) {
  (void)in_sizes; (void)n_in; (void)out_size;
  const float* x  = (const float*)d_in[0];
  const float* wq = (const float*)d_in[1];
  const float* wk = (const float*)d_in[2];
  const float* wv = (const float*)d_in[3];
  const float* wo = (const float*)d_in[4];
  float* out = (float*)d_out;

  const size_t SZ_X  = (size_t)MTOK * DMODEL * sizeof(f16);
  const size_t SZ_KV = (size_t)MTOK * NKV * HD * sizeof(f16);
  if (ws_size < 3 * SZ_X + 2 * SZ_KV) return;

  char* ws = (char*)d_ws;
  f16* xh  = (f16*)ws;                      // x f16; reused as ctx
  f16* wT  = (f16*)(ws + SZ_X);             // transposed weight (wq -> wk|wv -> wo)
  f16* Qb  = (f16*)(ws + 2 * SZ_X);
  f16* Kb  = (f16*)(ws + 3 * SZ_X);         // [B,S,NKV,HD]
  f16* VTb = (f16*)(ws + 3 * SZ_X + SZ_KV); // [B,NKV,HD,S] (right after Kb: MODE 3 relies on this)

  const float KSC2 = 0.08838834764831845f * 1.4426950408889634f;  // 1/sqrt(128)*log2(e)

  cvt_f32_f16_k<<<dim3(MTOK * DMODEL / 8 / 256), 256, 0, stream>>>(x, xh, MTOK * DMODEL / 8);

  // Q projection (wq prescaled by softmax scale -> attn needs no Q prescale)
  transpose_cvt_k<<<dim3(DMODEL / 32, DMODEL / 32), 256, 0, stream>>>(wq, wT, DMODEL, DMODEL, KSC2);
  gemm256_k<0><<<dim3((MTOK / 256) * (DMODEL / 256)), 512, 0, stream>>>(xh, wT, Qb, MTOK, DMODEL, DMODEL);

  // merged K|V projection: wT rows 0-1023 = wk^T, rows 1024-2047 = wv^T
  transpose_cvt_k<<<dim3(NKV * HD / 32, DMODEL / 32), 256, 0, stream>>>(wk, wT, DMODEL, NKV * HD, 1.0f);
  transpose_cvt_k<<<dim3(NKV * HD / 32, DMODEL / 32), 256, 0, stream>>>(wv, wT + (size_t)1024 * DMODEL, DMODEL, NKV * HD, 1.0f);
  gemm_bt_k<3><<<dim3((MTOK / 128) * (2048 / 128)), 256, 0, stream>>>(xh, wT, Kb, MTOK, 2048, DMODEL);

  attn_k7<<<dim3(BATCH * NKV * (SEQ / 32)), 512, 0, stream>>>(Qb, Kb, VTb, xh);

  transpose_cvt_k<<<dim3(DMODEL / 32, DMODEL / 32), 256, 0, stream>>>(wo, wT, DMODEL, DMODEL, 1.0f);
  gemm256_k<2><<<dim3((MTOK / 256) * (DMODEL / 256)), 512, 0, stream>>>(xh, wT, out, MTOK, DMODEL, DMODEL);
}